// Round 5
// baseline (233.479 us; speedup 1.0000x reference)
//
#include <hip/hip_runtime.h>
#include <cstdint>

typedef unsigned long long ull;

#define N_BOX 8192
#define CH 512        // chunk size
#define WPC 8         // words per chunk
#define NCH 16        // chunks

// ---------------- workspace layout ----------------
// TB (distance>=2 transposed col-blocks): 53760 rows * 64 B = 3,440,640 @ 0
// TC (superdiagonal transposed blocks):   15 * 32 KB        =   491,520 @ 3,440,640
// TD (per-chunk diagonal tables):         16 * 32 KB        =   524,288 @ 3,932,160
// boxes4 : 131072 @ 4,456,448
// scores : 32768  @ 4,587,520
// ctrl   : 68 KB  @ 4,620,288  (all flags/counters on private 128 B lines)
// keptg  : 16 chunks * 16 ull (128 B stride) @ 4,689,920
#define OFF_TB     0
#define OFF_TC     3440640
#define OFF_TD     3932160
#define OFF_BOXES  4456448
#define OFF_SCORES 4587520
#define OFF_CTRL   4620288
#define OFF_KEPT   4689920

#define CTRL_VB    512    // int index of vb
#define CNT_TD     1024   // + c*32  : TD[c] tiles done (expect 16)
#define CNT_TC     2048   // + c*32  : TC[c] tiles done (expect 16)
#define CNT_TB     3072   // + cp*32 : TB[cp] tiles done (expect 224-16cp)
#define KSTRIDE    16     // ull stride per chunk in keptg

// Agent(device)-scope accessors — the protocol rounds 2-4 proved cross-XCD.
#define A_LD(p)    __hip_atomic_load((p), __ATOMIC_RELAXED, __HIP_MEMORY_SCOPE_AGENT)
#define A_LDA(p)   __hip_atomic_load((p), __ATOMIC_ACQUIRE, __HIP_MEMORY_SCOPE_AGENT)
#define A_ST(p,v)  __hip_atomic_store((p), (v), __ATOMIC_RELAXED, __HIP_MEMORY_SCOPE_AGENT)
#define A_STR(p,v) __hip_atomic_store((p), (v), __ATOMIC_RELEASE, __HIP_MEMORY_SCOPE_AGENT)
#define A_INC(p)   __hip_atomic_fetch_add((p), 1, __ATOMIC_RELEASE, __HIP_MEMORY_SCOPE_AGENT)

// TB rows for source chunk c' cover j >= CH*(c'+2): 7168-512c' rows (c'=0..13)
__device__ __forceinline__ int rows_before2(int c) {
    return 7424 * c - 256 * c * c;   // sum_{c'<c} (7168 - 512c')
}

__device__ __forceinline__ ull make_key(float s, int idx) {
    // positive floats: bit pattern is order-preserving. Reversed index in the
    // low 13 bits reproduces stable argsort(-conf): equal conf -> lower index first.
    return (((ull)__float_as_uint(s)) << 13) | (ull)(8191 - idx);
}

__device__ __forceinline__ float box_area(float4 b) {
    return __fmul_rn(__fsub_rn(b.z, b.x), __fsub_rn(b.w, b.y));
}

// exact replica of reference IoU rounding (_rn ops block FMA contraction); symmetric.
__device__ __forceinline__ bool iou_gt_half(float4 a, float aarea, float4 b, float barea) {
    float ix1 = fmaxf(a.x, b.x);
    float iy1 = fmaxf(a.y, b.y);
    float ix2 = fminf(a.z, b.z);
    float iy2 = fminf(a.w, b.w);
    float iw = fmaxf(__fsub_rn(ix2, ix1), 0.0f);
    float ih = fmaxf(__fsub_rn(iy2, iy1), 0.0f);
    float inter = __fmul_rn(iw, ih);
    float uni = __fsub_rn(__fadd_rn(aarea, barea), inter);
    float iou = __fdiv_rn(inter, fmaxf(uni, 1e-9f));
    return iou > 0.5f;
}

// kA: fused max + rank + scatter (round-3 proven, passed). Block bx owns
// i in [bx*32, bx*32+32); rank via the PROVEN immediate-offset LDS loop.
// Block 0 zeroes ALL kB control state (flags + build counters) and vb.
__global__ __launch_bounds__(256) void k123_rank_scatter(const float* __restrict__ in,
                                                         float4* __restrict__ boxes4,
                                                         float* __restrict__ scores,
                                                         int* __restrict__ ctrl) {
    __shared__ ull keys[N_BOX];        // 64 KB
    __shared__ float wm[4];
    __shared__ int wv[4];
    int t = threadIdx.x;
    int bx = blockIdx.x;

    float cf[32];
    float m = 0.0f;                    // conf >= 0 so 0-seed is safe
    #pragma unroll
    for (int r = 0; r < 32; ++r) {
        cf[r] = in[(r * 256 + t) * 5 + 4];
        m = fmaxf(m, cf[r]);
    }
    for (int off = 32; off; off >>= 1) m = fmaxf(m, __shfl_down(m, off));
    if ((t & 63) == 0) wm[t >> 6] = m;
    __syncthreads();
    float maxc = fmaxf(fmaxf(wm[0], wm[1]), fmaxf(wm[2], wm[3]));

    #pragma unroll
    for (int r = 0; r < 32; ++r) {
        int k = r * 256 + t;
        keys[k] = make_key(__fdiv_rn(cf[r], maxc), k);
    }
    __syncthreads();

    int il = t >> 3, seg = t & 7;
    int i = bx * 32 + il;
    ull ki = keys[i];
    const ull* kb = keys + seg;
    int cnt = 0;
    #pragma unroll 8
    for (int cc = 0; cc < 1024; ++cc)
        cnt += (kb[cc * 8] > ki) ? 1 : 0;
    cnt += __shfl_down(cnt, 4, 8);
    cnt += __shfl_down(cnt, 2, 8);
    cnt += __shfl_down(cnt, 1, 8);

    if (seg == 0) {
        int r = cnt;                               // descending-sort position
        float cx = in[i * 5 + 0];
        float cy = in[i * 5 + 1];
        float w  = in[i * 5 + 2];
        float h  = in[i * 5 + 3];
        float s  = __fdiv_rn(in[i * 5 + 4], maxc);
        float4 b;
        b.x = __fsub_rn(cx, __fmul_rn(w, 0.5f));
        b.y = __fsub_rn(cy, __fmul_rn(h, 0.5f));
        b.z = __fadd_rn(cx, __fmul_rn(w, 0.5f));
        b.w = __fadd_rn(cy, __fmul_rn(h, 0.5f));
        boxes4[r] = b;
        scores[r] = s;
    }

    // block 0: vb + zero ALL kB flags/counters (poisoned workspace)
    if (bx == 0) {
        const ull kthr = ((ull)0x3F000000u) << 13;   // s >= 0.5 boundary
        int cv = 0;
        for (int k = t; k < N_BOX; k += 256) cv += (keys[k] >= kthr) ? 1 : 0;
        for (int off = 32; off; off >>= 1) cv += __shfl_down(cv, off);
        if ((t & 63) == 0) wv[t >> 6] = cv;
        if (t < NCH) ctrl[t * 32] = 0;               // chain flags
        if (t < NCH) ctrl[CNT_TD + t * 32] = 0;
        if (t < 15)  ctrl[CNT_TC + t * 32] = 0;
        if (t < 14)  ctrl[CNT_TB + t * 32] = 0;
        __syncthreads();
        if (t == 0) ctrl[CTRL_VB] = wv[0] + wv[1] + wv[2] + wv[3];
    }
}

// kB: merged table-build + chunk-chain NMS, ONE launch, NO global barrier.
//  blocks 16..255 = builders: 4 k4-tiles per block-iteration (sub-block s =
//    t>>8 handles tile 4g+s), tiles in CHAIN-PRIORITY order (all TD, then all
//    TC — both complete in builder-round 1 ~4us — then TB by cp ascending).
//    Completion signaled per region via padded release-counters.
//  blocks 0..15 = owners: block c stages TD[c]/TC[c-1] to LDS as soon as
//    their counters land (pre-chain, hidden), then runs the round-3 chain
//    verbatim: TB applies (A_LD rows) -> TC apply -> wave-0 TD fixpoint ->
//    publish keptg + flag. Epilogue writes own 512 rows.
// Bank-conflict fix (mega's 4.66M counter): IoU loop reads staggered
// kk=(k+w)&63 -> sb bank 4(k+w)%32, 8 distinct quads, conflict-free; bit
// position uses kk so the produced words are bit-identical.
__global__ __launch_bounds__(1024, 1) void kB_build_nms(const float4* __restrict__ boxes4,
                                                        const float* __restrict__ scores,
                                                        ull* __restrict__ TBg,
                                                        ull* __restrict__ TCg,
                                                        ull* __restrict__ TDg,
                                                        ull* __restrict__ keptg,
                                                        int* __restrict__ ctrl,
                                                        float* __restrict__ out) {
    __shared__ ull smem[8192];         // 64 KB union: builders sb/sa | owners TDs/TCs
    __shared__ unsigned amask[16];
    __shared__ ull kwsh[WPC];
    const int t = threadIdx.x;
    const int bx = blockIdx.x;

    if (bx >= 16) {
        // ================= builders =================
        float4* sb = (float4*)smem;            // [4][512] boxes   (32 KB)
        float*  sa = (float*)(smem + 4096);    // [4][512] areas   ( 8 KB)
        const int s  = t >> 8;                 // sub-block 0..3
        const int tl = t & 255;
        for (int g = bx - 16; g < 544; g += 240) {
            int p = 4 * g + s;                 // priority-ordered tile id
            int mode, c, j0;
            if (p < 256)      { mode = 2; c = p >> 4; j0 = (p & 15) * 32; }
            else if (p < 496) { mode = 1; int q = p - 256; c = q >> 4; j0 = (q & 15) * 32; }
            else { mode = 0; c = 0; int q = p - 496;
                   while (q >= 224 - 16 * c) { q -= 224 - 16 * c; ++c; }
                   j0 = CH * (c + 2) + q * 32; }
            bool live = scores[c * CH] >= 0.5f;             // dead source chunk
            if (mode == 0 && scores[j0] < 0.5f) live = false; // dead j-tile
            __syncthreads();                   // protect previous iteration's sb
            if (live) {
                for (int i = tl; i < CH; i += 256) {
                    float4 b = boxes4[c * CH + i];
                    sb[s * 512 + i] = b;
                    sa[s * 512 + i] = box_area(b);
                }
            }
            __syncthreads();
            if (live) {
                int w = tl & 7;
                int r = tl >> 3;
                int jl = j0 + r;               // mode 2/1: local row; mode 0: global j
                float4 me;
                float ma;
                int lim = 64;
                if (mode == 2) {
                    me = sb[s * 512 + jl];
                    ma = sa[s * 512 + jl];
                    int wj = jl >> 6;
                    lim = (w < wj) ? 64 : ((w == wj) ? (jl & 63) : 0);
                } else if (mode == 1) {
                    me = boxes4[CH * (c + 1) + jl];
                    ma = box_area(me);
                } else {
                    me = boxes4[jl];
                    ma = box_area(me);
                }
                ull bits = 0;
                #pragma unroll 8
                for (int k = 0; k < 64; ++k) {
                    int kk = (k + w) & 63;     // bank stagger: 4(k+w)%32, no conflict
                    if (kk < lim &&
                        iou_gt_half(sb[s * 512 + w * 64 + kk], sa[s * 512 + w * 64 + kk], me, ma))
                        bits |= 1ull << kk;
                }
                if (mode == 2)      A_ST(&TDg[c * 4096 + w * 512 + jl], bits);
                else if (mode == 1) A_ST(&TCg[c * 4096 + w * 512 + jl], bits);
                else A_ST(&TBg[(size_t)(rows_before2(c) + (jl - CH * (c + 2))) * WPC + w], bits);
            }
            __threadfence();                   // order table stores before signal
            __syncthreads();                   // all 4 sub-blocks' stores issued+fenced
            if (tl == 0) {
                int idx = (mode == 2) ? (CNT_TD + c * 32)
                        : (mode == 1) ? (CNT_TC + c * 32)
                        :               (CNT_TB + c * 32);
                A_INC(&ctrl[idx]);             // release: proven fence+barrier+signal
            }
        }
        return;
    }

    // ================= owners: chain block c =================
    const int c = bx;
    const int lane = t & 63;
    const int wave = t >> 6;
    int vb = ctrl[CTRL_VB];
    int nchv = (vb + CH - 1) / CH;

    if (c >= nchv) {                           // dead chunk: zero own 512 rows
        if (t < CH) {
            int j = c * CH + t;
            out[j * 5 + 0] = 0.0f; out[j * 5 + 1] = 0.0f; out[j * 5 + 2] = 0.0f;
            out[j * 5 + 3] = 0.0f; out[j * 5 + 4] = 0.0f;
        }
        return;
    }

    ull* TDs = smem;                           // 32 KB
    ull* TCs = smem + 4096;                    // 32 KB

    // ---- stage TD[c] as soon as built (pre-chain; hidden for c>0) ----
    if (t == 0) { while (A_LDA(&ctrl[CNT_TD + c * 32]) < 16) {} }
    __syncthreads();
    for (int i = t; i < 4096; i += 1024) TDs[i] = A_LD(&TDg[c * 4096 + i]);
    if (c > 0) {
        if (t == 0) { while (A_LDA(&ctrl[CNT_TC + (c - 1) * 32]) < 16) {} }
        __syncthreads();
        for (int i = t; i < 4096; i += 1024) TCs[i] = A_LD(&TCg[(c - 1) * 4096 + i]);
    }
    if (t < 16) {
        int n = vb - (c * 16 + t) * 32;
        amask[t] = (n >= 32) ? 0xffffffffu : ((n <= 0) ? 0u : ((1u << n) - 1u));
    }
    __syncthreads();

    // ---- TB applies: kept[cp] -> own chunk, cp = 0..c-2 ----
    for (int cp = 0; cp + 2 <= c; ++cp) {
        if (t == 0) {
            while (A_LDA(&ctrl[cp * 32]) != 1) {}                   // kept ready
            while (A_LDA(&ctrl[CNT_TB + cp * 32]) < 224 - 16 * cp) {} // rows built
            #pragma unroll
            for (int w = 0; w < WPC; ++w) kwsh[w] = A_LD(&keptg[cp * KSTRIDE + w]);
        }
        __syncthreads();
        ull anyk = kwsh[0] | kwsh[1] | kwsh[2] | kwsh[3] |
                   kwsh[4] | kwsh[5] | kwsh[6] | kwsh[7];
        if (anyk) {
            int jl = t & 511;
            int h  = t >> 9;                   // 2 threads per row, 4 words each
            if ((amask[jl >> 5] >> (jl & 31)) & 1u) {
                const ull* row = TBg +
                    (size_t)(rows_before2(cp) + (c * CH + jl - CH * (cp + 2))) * WPC;
                ull a = 0;
                #pragma unroll
                for (int q = 0; q < 4; ++q) a |= A_LD(&row[h * 4 + q]) & kwsh[h * 4 + q];
                if (a) atomicAnd(&amask[jl >> 5], ~(1u << (jl & 31)));
            }
        }
        __syncthreads();
    }

    // ---- TC apply: kept[c-1] -> own chunk (waves 0-7, one target word each) ----
    if (c > 0) {
        if (t == 0) {
            while (A_LDA(&ctrl[(c - 1) * 32]) != 1) {}
            #pragma unroll
            for (int w = 0; w < WPC; ++w) kwsh[w] = A_LD(&keptg[(c - 1) * KSTRIDE + w]);
        }
        __syncthreads();
        if (wave < WPC) {
            bool dead = false;
            #pragma unroll
            for (int w = 0; w < WPC; ++w) {
                ull kw = kwsh[w];
                if (kw) dead |= (TCs[w * 512 + wave * 64 + lane] & kw) != 0ull;
            }
            ull d = __ballot(dead);
            if (lane == 0 && d) {
                amask[2 * wave]     &= ~(unsigned)d;
                amask[2 * wave + 1] &= ~(unsigned)(d >> 32);
            }
        }
        __syncthreads();
    }

    // ---- scan own chunk (wave 0): TD fixpoint, then publish ----
    if (wave == 0) {
        ull alive[WPC];
        #pragma unroll
        for (int w = 0; w < WPC; ++w)
            alive[w] = (ull)amask[2 * w] | ((ull)amask[2 * w + 1] << 32);
        const ull* T = TDs;
        #pragma unroll
        for (int w = 0; w < WPC; ++w) {
            ull word = alive[w];
            if (!word) continue;
            ull Tc[WPC];
            #pragma unroll
            for (int j = 0; j < WPC; ++j)
                if (j >= w) Tc[j] = T[w * 512 + j * 64 + lane];
            ull td = Tc[w];
            ull a2 = word, kept = 0;
            while (a2 & ~kept) {
                bool al = (a2 >> lane) & 1;
                bool kp = (kept >> lane) & 1;
                ull nk = __ballot(al && !kp && ((td & a2) == 0));
                ull nd = __ballot(al && !kp && ((td & kept) != 0));
                kept |= nk;
                a2 &= ~nd;
            }
            alive[w] = kept;
            #pragma unroll
            for (int j = 0; j < WPC; ++j) {
                if (j <= w) continue;
                if (!alive[j]) continue;
                alive[j] &= ~__ballot((Tc[j] & kept) != 0);
            }
        }
        if (lane == 0) {
            #pragma unroll
            for (int w = 0; w < WPC; ++w) {
                A_ST(&keptg[c * KSTRIDE + w], alive[w]);
                amask[2 * w]     = (unsigned)alive[w];
                amask[2 * w + 1] = (unsigned)(alive[w] >> 32);
            }
            __threadfence();
            A_STR(&ctrl[c * 32], 1);
        }
    }
    __syncthreads();

    // ---- epilogue: own 512 output rows ----
    if (t < CH) {
        int j = c * CH + t;
        bool kept = (amask[t >> 5] >> (t & 31)) & 1u;
        float4 b = boxes4[j];
        float s = scores[j];
        out[j * 5 + 0] = kept ? b.x : 0.0f;
        out[j * 5 + 1] = kept ? b.y : 0.0f;
        out[j * 5 + 2] = kept ? b.z : 0.0f;
        out[j * 5 + 3] = kept ? b.w : 0.0f;
        out[j * 5 + 4] = kept ? s   : 0.0f;
    }
}

extern "C" void kernel_launch(void* const* d_in, const int* in_sizes, int n_in,
                              void* d_out, int out_size, void* d_ws, size_t ws_size,
                              hipStream_t stream) {
    const float* in = (const float*)d_in[0];
    char* ws = (char*)d_ws;
    ull* TB        = (ull*)(ws + OFF_TB);
    ull* TC        = (ull*)(ws + OFF_TC);
    ull* TD        = (ull*)(ws + OFF_TD);
    float4* boxes4 = (float4*)(ws + OFF_BOXES);
    float* scores  = (float*)(ws + OFF_SCORES);
    int* ctrl      = (int*)(ws + OFF_CTRL);
    ull* keptg     = (ull*)(ws + OFF_KEPT);
    float* out     = (float*)d_out;

    k123_rank_scatter<<<256, 256, 0, stream>>>(in, boxes4, scores, ctrl);
    kB_build_nms<<<256, 1024, 0, stream>>>(boxes4, scores, TB, TC, TD, keptg, ctrl, out);
}

// Round 6
// 127.895 us; speedup vs baseline: 1.8256x; 1.8256x over previous
//
#include <hip/hip_runtime.h>
#include <cstdint>

typedef unsigned long long ull;

#define N_BOX 8192
#define CH 512        // chunk size
#define WPC 8         // words per chunk
#define NCH 16        // chunks

// ---------------- workspace layout ----------------
// TB (distance>=2 transposed col-blocks): 53760 rows * 64 B = 3,440,640 @ 0
// TC (superdiagonal transposed blocks):   15 * 32 KB        =   491,520 @ 3,440,640
// TD (per-chunk diagonal tables):         16 * 32 KB        =   524,288 @ 3,932,160
// boxes4 : 131072 @ 4,456,448
// scores : 32768  @ 4,587,520
// ctrl   : flags on private 128 B lines @ 4,620,288
//          flagK[c] = int c*32 ; vb = int 512 ; flagP[c] = int 1024+c*32
// keptg  : 16 chunks * 16 ull (128 B stride) @ 4,689,920
// pusha  : 16 chunks * 16 ull (128 B stride) @ 4,691,968
#define OFF_TB     0
#define OFF_TC     3440640
#define OFF_TD     3932160
#define OFF_BOXES  4456448
#define OFF_SCORES 4587520
#define OFF_CTRL   4620288
#define OFF_KEPT   4689920
#define OFF_PUSH   4691968

#define CTRL_VB    512    // int index of vb
#define PFLAG      1024   // int index base of push flags (+c*32)
#define KSTRIDE    16     // ull stride per chunk in keptg/pusha

// Agent(device)-scope accessors — protocol proven cross-XCD in rounds 2-5.
#define A_LD(p)    __hip_atomic_load((p), __ATOMIC_RELAXED, __HIP_MEMORY_SCOPE_AGENT)
#define A_LDA(p)   __hip_atomic_load((p), __ATOMIC_ACQUIRE, __HIP_MEMORY_SCOPE_AGENT)
#define A_ST(p,v)  __hip_atomic_store((p), (v), __ATOMIC_RELAXED, __HIP_MEMORY_SCOPE_AGENT)
#define A_STR(p,v) __hip_atomic_store((p), (v), __ATOMIC_RELEASE, __HIP_MEMORY_SCOPE_AGENT)

// TB rows for source chunk c' cover j >= CH*(c'+2): 7168-512c' rows (c'=0..13)
__device__ __forceinline__ int rows_before2(int c) {
    return 7424 * c - 256 * c * c;   // sum_{c'<c} (7168 - 512c')
}

__device__ __forceinline__ ull make_key(float s, int idx) {
    // positive floats: bit pattern is order-preserving. Reversed index in the
    // low 13 bits reproduces stable argsort(-conf): equal conf -> lower index first.
    return (((ull)__float_as_uint(s)) << 13) | (ull)(8191 - idx);
}

__device__ __forceinline__ float box_area(float4 b) {
    return __fmul_rn(__fsub_rn(b.z, b.x), __fsub_rn(b.w, b.y));
}

// exact replica of reference IoU rounding (_rn ops block FMA contraction); symmetric.
__device__ __forceinline__ bool iou_gt_half(float4 a, float aarea, float4 b, float barea) {
    float ix1 = fmaxf(a.x, b.x);
    float iy1 = fmaxf(a.y, b.y);
    float ix2 = fminf(a.z, b.z);
    float iy2 = fminf(a.w, b.w);
    float iw = fmaxf(__fsub_rn(ix2, ix1), 0.0f);
    float ih = fmaxf(__fsub_rn(iy2, iy1), 0.0f);
    float inter = __fmul_rn(iw, ih);
    float uni = __fsub_rn(__fadd_rn(aarea, barea), inter);
    float iou = __fdiv_rn(inter, fmaxf(uni, 1e-9f));
    return iou > 0.5f;
}

// kA: fused max + rank + scatter (round-3 proven, passed). Block bx owns
// i in [bx*32, bx*32+32); rank via the PROVEN immediate-offset LDS loop.
// Block 0 zeroes the k5 chain flags (flagK + flagP) and publishes vb.
__global__ __launch_bounds__(256) void k123_rank_scatter(const float* __restrict__ in,
                                                         float4* __restrict__ boxes4,
                                                         float* __restrict__ scores,
                                                         int* __restrict__ ctrl) {
    __shared__ ull keys[N_BOX];        // 64 KB
    __shared__ float wm[4];
    __shared__ int wv[4];
    int t = threadIdx.x;
    int bx = blockIdx.x;

    float cf[32];
    float m = 0.0f;                    // conf >= 0 so 0-seed is safe
    #pragma unroll
    for (int r = 0; r < 32; ++r) {
        cf[r] = in[(r * 256 + t) * 5 + 4];
        m = fmaxf(m, cf[r]);
    }
    for (int off = 32; off; off >>= 1) m = fmaxf(m, __shfl_down(m, off));
    if ((t & 63) == 0) wm[t >> 6] = m;
    __syncthreads();
    float maxc = fmaxf(fmaxf(wm[0], wm[1]), fmaxf(wm[2], wm[3]));

    #pragma unroll
    for (int r = 0; r < 32; ++r) {
        int k = r * 256 + t;
        keys[k] = make_key(__fdiv_rn(cf[r], maxc), k);
    }
    __syncthreads();

    int il = t >> 3, seg = t & 7;
    int i = bx * 32 + il;
    ull ki = keys[i];
    const ull* kb = keys + seg;
    int cnt = 0;
    #pragma unroll 8
    for (int cc = 0; cc < 1024; ++cc)
        cnt += (kb[cc * 8] > ki) ? 1 : 0;
    cnt += __shfl_down(cnt, 4, 8);
    cnt += __shfl_down(cnt, 2, 8);
    cnt += __shfl_down(cnt, 1, 8);

    if (seg == 0) {
        int r = cnt;                               // descending-sort position
        float cx = in[i * 5 + 0];
        float cy = in[i * 5 + 1];
        float w  = in[i * 5 + 2];
        float h  = in[i * 5 + 3];
        float s  = __fdiv_rn(in[i * 5 + 4], maxc);
        float4 b;
        b.x = __fsub_rn(cx, __fmul_rn(w, 0.5f));
        b.y = __fsub_rn(cy, __fmul_rn(h, 0.5f));
        b.z = __fadd_rn(cx, __fmul_rn(w, 0.5f));
        b.w = __fadd_rn(cy, __fmul_rn(h, 0.5f));
        boxes4[r] = b;
        scores[r] = s;
    }

    // block 0: vb + zero chain flags (poisoned workspace)
    if (bx == 0) {
        const ull kthr = ((ull)0x3F000000u) << 13;   // s >= 0.5 boundary
        int cv = 0;
        for (int k = t; k < N_BOX; k += 256) cv += (keys[k] >= kthr) ? 1 : 0;
        for (int off = 32; off; off >>= 1) cv += __shfl_down(cv, off);
        if ((t & 63) == 0) wv[t >> 6] = cv;
        if (t < NCH) ctrl[t * 32] = 0;               // flagK
        if (t < NCH) ctrl[PFLAG + t * 32] = 0;       // flagP
        __syncthreads();
        if (t == 0) ctrl[CTRL_VB] = wv[0] + wv[1] + wv[2] + wv[3];
    }
}

// K4: build suppression bit tables (round-3 structure, 2176 blocks / 8 per CU
// TLP — proven fast). Only change: the IoU inner loop is bank-STAGGERED
// (kk=(k+w)&63 -> sb bank quad 4(k+w)%32, 8 distinct across the 8 w-groups;
// bit position uses kk so outputs are bit-identical — proven PASS in R5).
__global__ __launch_bounds__(256) void k4_build(const float4* __restrict__ boxes4,
                                                const float* __restrict__ scores,
                                                ull* __restrict__ TB,
                                                ull* __restrict__ TC,
                                                ull* __restrict__ TD) {
    __shared__ float4 sb[CH];
    __shared__ float sa[CH];
    int bid = blockIdx.x;
    int t = threadIdx.x;
    int c;
    int mode;   // 0=TB, 1=TC, 2=TD
    int j0;     // TB: global j tile start; TC/TD: local jl tile start
    if (bid >= 1920) {
        mode = 2;
        int d = bid - 1920;
        c = d >> 4;
        j0 = (d & 15) * 32;
    } else if (bid >= 1680) {
        mode = 1;
        int d = bid - 1680;
        c = d >> 4;          // 0..14
        j0 = (d & 15) * 32;
    } else {
        mode = 0;
        c = 0;
        int rem = bid;
        while (rem >= 224 - 16 * c) { rem -= 224 - 16 * c; ++c; }
        j0 = CH * (c + 2) + rem * 32;
    }
    if (scores[c * CH] < 0.5f) return;               // source chunk never a suppressor
    if (mode == 0 && scores[j0] < 0.5f) return;      // j-tile never alive (desc scores)

    for (int i = t; i < CH; i += 256) {
        float4 b = boxes4[c * CH + i];
        sb[i] = b;
        sa[i] = box_area(b);
    }
    __syncthreads();

    int w = t & 7;
    int r = t >> 3;          // 0..31 local row
    int jl = j0 + r;         // mode 2/1: local row; mode 0: global j
    float4 me;
    float ma;
    int lim = 64;
    if (mode == 2) {
        me = sb[jl];
        ma = sa[jl];
        int wj = jl >> 6;
        lim = (w < wj) ? 64 : ((w == wj) ? (jl & 63) : 0);
    } else if (mode == 1) {
        me = boxes4[CH * (c + 1) + jl];
        ma = box_area(me);
    } else {
        me = boxes4[jl];
        ma = box_area(me);
    }
    ull bits = 0;
    #pragma unroll 8
    for (int k = 0; k < 64; ++k) {
        int kk = (k + w) & 63;         // bank stagger, bit-identical output
        if (kk < lim &&
            iou_gt_half(sb[w * 64 + kk], sa[w * 64 + kk], me, ma))
            bits |= 1ull << kk;
    }
    if (mode == 2)      TD[c * 4096 + w * 512 + jl] = bits;
    else if (mode == 1) TC[c * 4096 + w * 512 + jl] = bits;
    else TB[(size_t)(rows_before2(c) + (jl - CH * (c + 2))) * WPC + w] = bits;
}

// K5: pipelined multi-block greedy NMS, block c owns chunk c.
// Round-6 change: PRODUCER-PUSH handoff. Owner c stages TC[c] (its boxes vs
// chunk c+1); after publishing kept[c] (flagK, for TB consumers) it performs
// the TC apply FOR chunk c+1 (8 waves, LDS) and pushes the 8 suppression
// words + release flagP[c+1]. Consumer c's critical step collapses to:
// spin flagP[c] -> read 8 words -> AND into amask -> scan. This removes the
// consumer-side kept round-trip + apply barrier pair from every chain step.
// All other phases (TB applies, TD fixpoint scan, publish) are R3-verbatim.
__global__ __launch_bounds__(1024) void k5_nms(const float4* __restrict__ boxes4,
                                               const float* __restrict__ scores,
                                               const ull* __restrict__ TBg,
                                               const ull* __restrict__ TCg,
                                               const ull* __restrict__ TDg,
                                               ull* __restrict__ keptg,
                                               ull* __restrict__ pusha,
                                               int* __restrict__ ctrl,
                                               float* __restrict__ out) {
    __shared__ ull TDs[CH * WPC];      // 32 KB: TD[c]
    __shared__ ull TCs[CH * WPC];      // 32 KB: TC[c]  (push source, c -> c+1)
    __shared__ ull kwsh[WPC];
    __shared__ ull darr[WPC];
    __shared__ unsigned amask[16];     // 512 alive bits for own chunk
    int c = blockIdx.x;
    int t = threadIdx.x;
    int lane = t & 63;
    int wave = t >> 6;
    int vb = ctrl[CTRL_VB];
    int nchv = (vb + CH - 1) / CH;

    if (c < nchv) {
        // ---- stage TD[c] (and TC[c] if we will push); init alive mask ----
        {
            const ulonglong2* src = (const ulonglong2*)(TDg + (size_t)c * CH * WPC);
            ulonglong2* dst = (ulonglong2*)TDs;
            #pragma unroll
            for (int i2 = t; i2 < CH * WPC / 2; i2 += 1024) dst[i2] = src[i2];
        }
        if (c + 1 < nchv) {
            const ulonglong2* src = (const ulonglong2*)(TCg + (size_t)c * CH * WPC);
            ulonglong2* dst = (ulonglong2*)TCs;
            #pragma unroll
            for (int i2 = t; i2 < CH * WPC / 2; i2 += 1024) dst[i2] = src[i2];
        }
        if (t < 16) {
            int n = vb - (c * 16 + t) * 32;
            amask[t] = (n >= 32) ? 0xffffffffu : ((n <= 0) ? 0u : ((1u << n) - 1u));
        }
        __syncthreads();

        // ---- TB applies: kept[cp] -> own chunk, cp = 0..c-2 (R3-verbatim) ----
        for (int cp = 0; cp + 2 <= c; ++cp) {
            if (t == 0) {
                while (A_LDA(&ctrl[cp * 32]) != 1) {}
                #pragma unroll
                for (int w = 0; w < WPC; ++w) kwsh[w] = A_LD(&keptg[cp * KSTRIDE + w]);
            }
            __syncthreads();
            ull anyk = kwsh[0] | kwsh[1] | kwsh[2] | kwsh[3] |
                       kwsh[4] | kwsh[5] | kwsh[6] | kwsh[7];
            if (anyk && t < CH) {
                if ((amask[t >> 5] >> (t & 31)) & 1u) {
                    const ull* row = TBg +
                        (size_t)(rows_before2(cp) + (c * CH + t - CH * (cp + 2))) * WPC;
                    ull a = 0;
                    #pragma unroll
                    for (int q = 0; q < WPC; ++q) a |= row[q] & kwsh[q];
                    if (a) atomicAnd(&amask[t >> 5], ~(1u << (t & 31)));
                }
            }
            __syncthreads();
        }

        // ---- pushed TC suppression from owner c-1 (replaces local TC apply) ----
        if (c > 0) {
            if (t == 0) {
                while (A_LDA(&ctrl[PFLAG + c * 32]) != 1) {}
                #pragma unroll
                for (int w = 0; w < WPC; ++w) kwsh[w] = A_LD(&pusha[c * KSTRIDE + w]);
            }
            __syncthreads();
            if (t < WPC) {
                ull s = kwsh[t];
                amask[2 * t]     &= ~(unsigned)s;
                amask[2 * t + 1] &= ~(unsigned)(s >> 32);
            }
            __syncthreads();
        }

        // ---- scan own chunk (wave 0): TD fixpoint, then publish (R3-verbatim) ----
        if (wave == 0) {
            ull alive[WPC];
            #pragma unroll
            for (int w = 0; w < WPC; ++w)
                alive[w] = (ull)amask[2 * w] | ((ull)amask[2 * w + 1] << 32);
            const ull* T = TDs;
            #pragma unroll
            for (int w = 0; w < WPC; ++w) {
                ull word = alive[w];
                if (!word) continue;
                ull Tc[WPC];
                #pragma unroll
                for (int j = 0; j < WPC; ++j)
                    if (j >= w) Tc[j] = T[w * 512 + j * 64 + lane];
                ull td = Tc[w];
                ull a2 = word, kept = 0;
                while (a2 & ~kept) {
                    bool al = (a2 >> lane) & 1;
                    bool kp = (kept >> lane) & 1;
                    ull nk = __ballot(al && !kp && ((td & a2) == 0));
                    ull nd = __ballot(al && !kp && ((td & kept) != 0));
                    kept |= nk;
                    a2 &= ~nd;
                }
                alive[w] = kept;
                #pragma unroll
                for (int j = 0; j < WPC; ++j) {
                    if (j <= w) continue;
                    if (!alive[j]) continue;
                    alive[j] &= ~__ballot((Tc[j] & kept) != 0);
                }
            }
            if (lane == 0) {
                #pragma unroll
                for (int w = 0; w < WPC; ++w) {
                    A_ST(&keptg[c * KSTRIDE + w], alive[w]);
                    amask[2 * w]     = (unsigned)alive[w];
                    amask[2 * w + 1] = (unsigned)(alive[w] >> 32);
                }
                __threadfence();
                A_STR(&ctrl[c * 32], 1);          // flagK: TB consumers unblock first
            }
        }
        __syncthreads();

        // ---- producer push: TC apply for chunk c+1, publish suppression ----
        if (c + 1 < nchv) {
            if (wave < WPC) {
                ull kw[WPC];
                #pragma unroll
                for (int w = 0; w < WPC; ++w)
                    kw[w] = (ull)amask[2 * w] | ((ull)amask[2 * w + 1] << 32);
                bool dead = false;
                #pragma unroll
                for (int w = 0; w < WPC; ++w) {
                    if (kw[w]) dead |= (TCs[w * 512 + wave * 64 + lane] & kw[w]) != 0ull;
                }
                ull d = __ballot(dead);
                if (lane == 0) darr[wave] = d;
            }
            __syncthreads();
            if (t == 0) {
                #pragma unroll
                for (int w = 0; w < WPC; ++w)
                    A_ST(&pusha[(c + 1) * KSTRIDE + w], darr[w]);
                __threadfence();
                A_STR(&ctrl[PFLAG + (c + 1) * 32], 1);
            }
        }
        __syncthreads();
    } else {
        if (t < 16) amask[t] = 0u;
        __syncthreads();
    }

    // ---- epilogue: write own 512 output rows ----
    if (t < CH) {
        int j = c * CH + t;
        bool kept = (amask[t >> 5] >> (t & 31)) & 1u;
        float4 b = boxes4[j];
        float s = scores[j];
        out[j * 5 + 0] = kept ? b.x : 0.0f;
        out[j * 5 + 1] = kept ? b.y : 0.0f;
        out[j * 5 + 2] = kept ? b.z : 0.0f;
        out[j * 5 + 3] = kept ? b.w : 0.0f;
        out[j * 5 + 4] = kept ? s   : 0.0f;
    }
}

extern "C" void kernel_launch(void* const* d_in, const int* in_sizes, int n_in,
                              void* d_out, int out_size, void* d_ws, size_t ws_size,
                              hipStream_t stream) {
    const float* in = (const float*)d_in[0];
    char* ws = (char*)d_ws;
    ull* TB        = (ull*)(ws + OFF_TB);
    ull* TC        = (ull*)(ws + OFF_TC);
    ull* TD        = (ull*)(ws + OFF_TD);
    float4* boxes4 = (float4*)(ws + OFF_BOXES);
    float* scores  = (float*)(ws + OFF_SCORES);
    int* ctrl      = (int*)(ws + OFF_CTRL);
    ull* keptg     = (ull*)(ws + OFF_KEPT);
    ull* pusha     = (ull*)(ws + OFF_PUSH);
    float* out     = (float*)d_out;

    k123_rank_scatter<<<256, 256, 0, stream>>>(in, boxes4, scores, ctrl);
    k4_build<<<2176, 256, 0, stream>>>(boxes4, scores, TB, TC, TD);
    k5_nms<<<NCH, 1024, 0, stream>>>(boxes4, scores, TB, TC, TD, keptg, pusha, ctrl, out);
}

// Round 7
// 121.390 us; speedup vs baseline: 1.9234x; 1.0536x over previous
//
#include <hip/hip_runtime.h>
#include <cstdint>

typedef unsigned long long ull;

#define N_BOX 8192
#define CH 512        // chunk size
#define WPC 8         // words per chunk
#define NCH 16        // chunks

// ---------------- workspace layout ----------------
// TB (distance>=2 transposed col-blocks): 53760 rows * 64 B = 3,440,640 @ 0
// TC (superdiagonal transposed blocks):   15 * 32 KB        =   491,520 @ 3,440,640
// TD (per-chunk diagonal tables):         16 * 32 KB        =   524,288 @ 3,932,160
// boxes4 : 131072 @ 4,456,448
// scores : 32768  @ 4,587,520
// ctrl   : flags on private 128 B lines @ 4,620,288
//          flagK[c] = int c*32 ; vb = int 512 ; flagP[c] = int 1024+c*32
// keptg  : 16 chunks * 16 ull (128 B stride) @ 4,689,920
// pusha  : 16 chunks * 16 ull (128 B stride) @ 4,691,968
#define OFF_TB     0
#define OFF_TC     3440640
#define OFF_TD     3932160
#define OFF_BOXES  4456448
#define OFF_SCORES 4587520
#define OFF_CTRL   4620288
#define OFF_KEPT   4689920
#define OFF_PUSH   4691968

#define CTRL_VB    512    // int index of vb
#define PFLAG      1024   // int index base of push flags (+c*32)
#define KSTRIDE    16     // ull stride per chunk in keptg/pusha

// Agent(device)-scope accessors. CRITICAL (round-7 finding): agent-scope
// ACQUIRE loads emit a per-poll L2-invalidate (buffer_inv) on gfx950 — a
// spin loop of them stalls the memory pipe and evicts the staged tables
// chip-wide (R6: 592 KB HBM refetch, ~5 us/chain-hop, VALUBusy 0.07%).
// All cross-block k5 data moves via sc1 atomics (coherent at MALL), and all
// cached reads come from PRIOR kernels (coherent at launch boundary), so
// RELAXED polling is sufficient: it still reads the coherence point, but
// emits no invalidate. Release stores (A_STR) keep their own ordering.
#define A_LD(p)    __hip_atomic_load((p), __ATOMIC_RELAXED, __HIP_MEMORY_SCOPE_AGENT)
#define A_ST(p,v)  __hip_atomic_store((p), (v), __ATOMIC_RELAXED, __HIP_MEMORY_SCOPE_AGENT)
#define A_STR(p,v) __hip_atomic_store((p), (v), __ATOMIC_RELEASE, __HIP_MEMORY_SCOPE_AGENT)

// TB rows for source chunk c' cover j >= CH*(c'+2): 7168-512c' rows (c'=0..13)
__device__ __forceinline__ int rows_before2(int c) {
    return 7424 * c - 256 * c * c;   // sum_{c'<c} (7168 - 512c')
}

__device__ __forceinline__ ull make_key(float s, int idx) {
    // positive floats: bit pattern is order-preserving. Reversed index in the
    // low 13 bits reproduces stable argsort(-conf): equal conf -> lower index first.
    return (((ull)__float_as_uint(s)) << 13) | (ull)(8191 - idx);
}

__device__ __forceinline__ float box_area(float4 b) {
    return __fmul_rn(__fsub_rn(b.z, b.x), __fsub_rn(b.w, b.y));
}

// exact replica of reference IoU rounding (_rn ops block FMA contraction); symmetric.
__device__ __forceinline__ bool iou_gt_half(float4 a, float aarea, float4 b, float barea) {
    float ix1 = fmaxf(a.x, b.x);
    float iy1 = fmaxf(a.y, b.y);
    float ix2 = fminf(a.z, b.z);
    float iy2 = fminf(a.w, b.w);
    float iw = fmaxf(__fsub_rn(ix2, ix1), 0.0f);
    float ih = fmaxf(__fsub_rn(iy2, iy1), 0.0f);
    float inter = __fmul_rn(iw, ih);
    float uni = __fsub_rn(__fadd_rn(aarea, barea), inter);
    float iou = __fdiv_rn(inter, fmaxf(uni, 1e-9f));
    return iou > 0.5f;
}

// kA: fused max + rank + scatter (round-3 proven, passed). Block bx owns
// i in [bx*32, bx*32+32); rank via the PROVEN immediate-offset LDS loop.
// Block 0 zeroes the k5 chain flags (flagK + flagP) and publishes vb.
__global__ __launch_bounds__(256) void k123_rank_scatter(const float* __restrict__ in,
                                                         float4* __restrict__ boxes4,
                                                         float* __restrict__ scores,
                                                         int* __restrict__ ctrl) {
    __shared__ ull keys[N_BOX];        // 64 KB
    __shared__ float wm[4];
    __shared__ int wv[4];
    int t = threadIdx.x;
    int bx = blockIdx.x;

    float cf[32];
    float m = 0.0f;                    // conf >= 0 so 0-seed is safe
    #pragma unroll
    for (int r = 0; r < 32; ++r) {
        cf[r] = in[(r * 256 + t) * 5 + 4];
        m = fmaxf(m, cf[r]);
    }
    for (int off = 32; off; off >>= 1) m = fmaxf(m, __shfl_down(m, off));
    if ((t & 63) == 0) wm[t >> 6] = m;
    __syncthreads();
    float maxc = fmaxf(fmaxf(wm[0], wm[1]), fmaxf(wm[2], wm[3]));

    #pragma unroll
    for (int r = 0; r < 32; ++r) {
        int k = r * 256 + t;
        keys[k] = make_key(__fdiv_rn(cf[r], maxc), k);
    }
    __syncthreads();

    int il = t >> 3, seg = t & 7;
    int i = bx * 32 + il;
    ull ki = keys[i];
    const ull* kb = keys + seg;
    int cnt = 0;
    #pragma unroll 8
    for (int cc = 0; cc < 1024; ++cc)
        cnt += (kb[cc * 8] > ki) ? 1 : 0;
    cnt += __shfl_down(cnt, 4, 8);
    cnt += __shfl_down(cnt, 2, 8);
    cnt += __shfl_down(cnt, 1, 8);

    if (seg == 0) {
        int r = cnt;                               // descending-sort position
        float cx = in[i * 5 + 0];
        float cy = in[i * 5 + 1];
        float w  = in[i * 5 + 2];
        float h  = in[i * 5 + 3];
        float s  = __fdiv_rn(in[i * 5 + 4], maxc);
        float4 b;
        b.x = __fsub_rn(cx, __fmul_rn(w, 0.5f));
        b.y = __fsub_rn(cy, __fmul_rn(h, 0.5f));
        b.z = __fadd_rn(cx, __fmul_rn(w, 0.5f));
        b.w = __fadd_rn(cy, __fmul_rn(h, 0.5f));
        boxes4[r] = b;
        scores[r] = s;
    }

    // block 0: vb + zero chain flags (poisoned workspace)
    if (bx == 0) {
        const ull kthr = ((ull)0x3F000000u) << 13;   // s >= 0.5 boundary
        int cv = 0;
        for (int k = t; k < N_BOX; k += 256) cv += (keys[k] >= kthr) ? 1 : 0;
        for (int off = 32; off; off >>= 1) cv += __shfl_down(cv, off);
        if ((t & 63) == 0) wv[t >> 6] = cv;
        if (t < NCH) ctrl[t * 32] = 0;               // flagK
        if (t < NCH) ctrl[PFLAG + t * 32] = 0;       // flagP
        __syncthreads();
        if (t == 0) ctrl[CTRL_VB] = wv[0] + wv[1] + wv[2] + wv[3];
    }
}

// K4: build suppression bit tables (round-3 structure, 2176 blocks / 8 per CU
// TLP — proven fast). IoU inner loop bank-STAGGERED (kk=(k+w)&63; 8 distinct
// bank quads across the 8 w-groups; bit-identical output — proven PASS R5/R6).
__global__ __launch_bounds__(256) void k4_build(const float4* __restrict__ boxes4,
                                                const float* __restrict__ scores,
                                                ull* __restrict__ TB,
                                                ull* __restrict__ TC,
                                                ull* __restrict__ TD) {
    __shared__ float4 sb[CH];
    __shared__ float sa[CH];
    int bid = blockIdx.x;
    int t = threadIdx.x;
    int c;
    int mode;   // 0=TB, 1=TC, 2=TD
    int j0;     // TB: global j tile start; TC/TD: local jl tile start
    if (bid >= 1920) {
        mode = 2;
        int d = bid - 1920;
        c = d >> 4;
        j0 = (d & 15) * 32;
    } else if (bid >= 1680) {
        mode = 1;
        int d = bid - 1680;
        c = d >> 4;          // 0..14
        j0 = (d & 15) * 32;
    } else {
        mode = 0;
        c = 0;
        int rem = bid;
        while (rem >= 224 - 16 * c) { rem -= 224 - 16 * c; ++c; }
        j0 = CH * (c + 2) + rem * 32;
    }
    if (scores[c * CH] < 0.5f) return;               // source chunk never a suppressor
    if (mode == 0 && scores[j0] < 0.5f) return;      // j-tile never alive (desc scores)

    for (int i = t; i < CH; i += 256) {
        float4 b = boxes4[c * CH + i];
        sb[i] = b;
        sa[i] = box_area(b);
    }
    __syncthreads();

    int w = t & 7;
    int r = t >> 3;          // 0..31 local row
    int jl = j0 + r;         // mode 2/1: local row; mode 0: global j
    float4 me;
    float ma;
    int lim = 64;
    if (mode == 2) {
        me = sb[jl];
        ma = sa[jl];
        int wj = jl >> 6;
        lim = (w < wj) ? 64 : ((w == wj) ? (jl & 63) : 0);
    } else if (mode == 1) {
        me = boxes4[CH * (c + 1) + jl];
        ma = box_area(me);
    } else {
        me = boxes4[jl];
        ma = box_area(me);
    }
    ull bits = 0;
    #pragma unroll 8
    for (int k = 0; k < 64; ++k) {
        int kk = (k + w) & 63;         // bank stagger, bit-identical output
        if (kk < lim &&
            iou_gt_half(sb[w * 64 + kk], sa[w * 64 + kk], me, ma))
            bits |= 1ull << kk;
    }
    if (mode == 2)      TD[c * 4096 + w * 512 + jl] = bits;
    else if (mode == 1) TC[c * 4096 + w * 512 + jl] = bits;
    else TB[(size_t)(rows_before2(c) + (jl - CH * (c + 2))) * WPC + w] = bits;
}

// K5: pipelined multi-block greedy NMS, block c owns chunk c. R6 structure
// (producer-push handoff) with the round-7 sync fixes:
//  - ALL spins are RELAXED agent loads (sc1, read MALL, NO per-poll L2 inv)
//  - kept/push word reads parallelized across lanes 0-7 (wave-divergence
//    reconvergence guarantees they issue after lane 0's spin completes)
//  - no explicit __threadfence(): the A_STR release store already orders the
//    prior sc1 data stores (wave-level vmcnt wait); the extra fence was a
//    redundant L2 writeback+invalidate per hop
__global__ __launch_bounds__(1024) void k5_nms(const float4* __restrict__ boxes4,
                                               const float* __restrict__ scores,
                                               const ull* __restrict__ TBg,
                                               const ull* __restrict__ TCg,
                                               const ull* __restrict__ TDg,
                                               ull* __restrict__ keptg,
                                               ull* __restrict__ pusha,
                                               int* __restrict__ ctrl,
                                               float* __restrict__ out) {
    __shared__ ull TDs[CH * WPC];      // 32 KB: TD[c]
    __shared__ ull TCs[CH * WPC];      // 32 KB: TC[c]  (push source, c -> c+1)
    __shared__ ull kwsh[WPC];
    __shared__ ull darr[WPC];
    __shared__ unsigned amask[16];     // 512 alive bits for own chunk
    int c = blockIdx.x;
    int t = threadIdx.x;
    int lane = t & 63;
    int wave = t >> 6;
    int vb = ctrl[CTRL_VB];
    int nchv = (vb + CH - 1) / CH;

    if (c < nchv) {
        // ---- stage TD[c] (and TC[c] if we will push); init alive mask ----
        {
            const ulonglong2* src = (const ulonglong2*)(TDg + (size_t)c * CH * WPC);
            ulonglong2* dst = (ulonglong2*)TDs;
            #pragma unroll
            for (int i2 = t; i2 < CH * WPC / 2; i2 += 1024) dst[i2] = src[i2];
        }
        if (c + 1 < nchv) {
            const ulonglong2* src = (const ulonglong2*)(TCg + (size_t)c * CH * WPC);
            ulonglong2* dst = (ulonglong2*)TCs;
            #pragma unroll
            for (int i2 = t; i2 < CH * WPC / 2; i2 += 1024) dst[i2] = src[i2];
        }
        if (t < 16) {
            int n = vb - (c * 16 + t) * 32;
            amask[t] = (n >= 32) ? 0xffffffffu : ((n <= 0) ? 0u : ((1u << n) - 1u));
        }
        __syncthreads();

        // ---- TB applies: kept[cp] -> own chunk, cp = 0..c-2 ----
        for (int cp = 0; cp + 2 <= c; ++cp) {
            if (wave == 0) {
                if (lane == 0) { while (A_LD(&ctrl[cp * 32]) != 1) {} }
                // reconvergence: lanes 0-7 load only after the spin exits
                if (lane < WPC) kwsh[lane] = A_LD(&keptg[cp * KSTRIDE + lane]);
            }
            __syncthreads();
            ull anyk = kwsh[0] | kwsh[1] | kwsh[2] | kwsh[3] |
                       kwsh[4] | kwsh[5] | kwsh[6] | kwsh[7];
            if (anyk && t < CH) {
                if ((amask[t >> 5] >> (t & 31)) & 1u) {
                    const ull* row = TBg +
                        (size_t)(rows_before2(cp) + (c * CH + t - CH * (cp + 2))) * WPC;
                    ull a = 0;
                    #pragma unroll
                    for (int q = 0; q < WPC; ++q) a |= row[q] & kwsh[q];
                    if (a) atomicAnd(&amask[t >> 5], ~(1u << (t & 31)));
                }
            }
            __syncthreads();
        }

        // ---- pushed TC suppression from owner c-1 (replaces local TC apply) ----
        if (c > 0) {
            if (wave == 0) {
                if (lane == 0) { while (A_LD(&ctrl[PFLAG + c * 32]) != 1) {} }
                if (lane < WPC) kwsh[lane] = A_LD(&pusha[c * KSTRIDE + lane]);
            }
            __syncthreads();
            if (t < WPC) {
                ull s = kwsh[t];
                amask[2 * t]     &= ~(unsigned)s;
                amask[2 * t + 1] &= ~(unsigned)(s >> 32);
            }
            __syncthreads();
        }

        // ---- scan own chunk (wave 0): TD fixpoint, then publish ----
        if (wave == 0) {
            ull alive[WPC];
            #pragma unroll
            for (int w = 0; w < WPC; ++w)
                alive[w] = (ull)amask[2 * w] | ((ull)amask[2 * w + 1] << 32);
            const ull* T = TDs;
            #pragma unroll
            for (int w = 0; w < WPC; ++w) {
                ull word = alive[w];
                if (!word) continue;
                ull Tc[WPC];
                #pragma unroll
                for (int j = 0; j < WPC; ++j)
                    if (j >= w) Tc[j] = T[w * 512 + j * 64 + lane];
                ull td = Tc[w];
                ull a2 = word, kept = 0;
                while (a2 & ~kept) {
                    bool al = (a2 >> lane) & 1;
                    bool kp = (kept >> lane) & 1;
                    ull nk = __ballot(al && !kp && ((td & a2) == 0));
                    ull nd = __ballot(al && !kp && ((td & kept) != 0));
                    kept |= nk;
                    a2 &= ~nd;
                }
                alive[w] = kept;
                #pragma unroll
                for (int j = 0; j < WPC; ++j) {
                    if (j <= w) continue;
                    if (!alive[j]) continue;
                    alive[j] &= ~__ballot((Tc[j] & kept) != 0);
                }
            }
            if (lane == 0) {
                #pragma unroll
                for (int w = 0; w < WPC; ++w) {
                    A_ST(&keptg[c * KSTRIDE + w], alive[w]);
                    amask[2 * w]     = (unsigned)alive[w];
                    amask[2 * w + 1] = (unsigned)(alive[w] >> 32);
                }
                A_STR(&ctrl[c * 32], 1);          // release orders the 8 stores
            }
        }
        __syncthreads();

        // ---- producer push: TC apply for chunk c+1, publish suppression ----
        if (c + 1 < nchv) {
            if (wave < WPC) {
                ull kw[WPC];
                #pragma unroll
                for (int w = 0; w < WPC; ++w)
                    kw[w] = (ull)amask[2 * w] | ((ull)amask[2 * w + 1] << 32);
                bool dead = false;
                #pragma unroll
                for (int w = 0; w < WPC; ++w) {
                    if (kw[w]) dead |= (TCs[w * 512 + wave * 64 + lane] & kw[w]) != 0ull;
                }
                ull d = __ballot(dead);
                if (lane == 0) darr[wave] = d;
            }
            __syncthreads();
            if (t == 0) {
                #pragma unroll
                for (int w = 0; w < WPC; ++w)
                    A_ST(&pusha[(c + 1) * KSTRIDE + w], darr[w]);
                A_STR(&ctrl[PFLAG + (c + 1) * 32], 1);   // release orders them
            }
        }
        __syncthreads();
    } else {
        if (t < 16) amask[t] = 0u;
        __syncthreads();
    }

    // ---- epilogue: write own 512 output rows ----
    if (t < CH) {
        int j = c * CH + t;
        bool kept = (amask[t >> 5] >> (t & 31)) & 1u;
        float4 b = boxes4[j];
        float s = scores[j];
        out[j * 5 + 0] = kept ? b.x : 0.0f;
        out[j * 5 + 1] = kept ? b.y : 0.0f;
        out[j * 5 + 2] = kept ? b.z : 0.0f;
        out[j * 5 + 3] = kept ? b.w : 0.0f;
        out[j * 5 + 4] = kept ? s   : 0.0f;
    }
}

extern "C" void kernel_launch(void* const* d_in, const int* in_sizes, int n_in,
                              void* d_out, int out_size, void* d_ws, size_t ws_size,
                              hipStream_t stream) {
    const float* in = (const float*)d_in[0];
    char* ws = (char*)d_ws;
    ull* TB        = (ull*)(ws + OFF_TB);
    ull* TC        = (ull*)(ws + OFF_TC);
    ull* TD        = (ull*)(ws + OFF_TD);
    float4* boxes4 = (float4*)(ws + OFF_BOXES);
    float* scores  = (float*)(ws + OFF_SCORES);
    int* ctrl      = (int*)(ws + OFF_CTRL);
    ull* keptg     = (ull*)(ws + OFF_KEPT);
    ull* pusha     = (ull*)(ws + OFF_PUSH);
    float* out     = (float*)d_out;

    k123_rank_scatter<<<256, 256, 0, stream>>>(in, boxes4, scores, ctrl);
    k4_build<<<2176, 256, 0, stream>>>(boxes4, scores, TB, TC, TD);
    k5_nms<<<NCH, 1024, 0, stream>>>(boxes4, scores, TB, TC, TD, keptg, pusha, ctrl, out);
}